// Round 1
// baseline (499.436 us; speedup 1.0000x reference)
//
#include <hip/hip_runtime.h>
#include <hip/hip_bf16.h>

// Problem constants (fixed by reference):
//   B=4, T=2048, C=1024, H=16, Dh=64, qkv N = 3072, M = B*T = 8192.
#define T_SEQ 2048
#define D_EMB 1024
#define NH    16
#define DH    64
#define NB    4
#define MROWS (NB * T_SEQ)      // 8192
#define QKVN  (3 * D_EMB)       // 3072

typedef __attribute__((ext_vector_type(8))) short bf16x8;   // 8 bf16 = 4 VGPR (guide-verified frag type)
typedef __attribute__((ext_vector_type(4))) float f32x4;

__device__ __forceinline__ unsigned short f2bf(float f) {
  __hip_bfloat16 h = __float2bfloat16(f);
  return __builtin_bit_cast(unsigned short, h);
}

__device__ __forceinline__ void gload_lds16(const void* g, void* lds) {
  // async global->LDS, 16B/lane; LDS dest must be wave-uniform base (HW adds lane*16)
  __builtin_amdgcn_global_load_lds(
      (const __attribute__((address_space(1))) void*)g,
      (__attribute__((address_space(3))) void*)lds, 16, 0, 0);
}

__device__ __forceinline__ float redmax16(float v) {
  v = fmaxf(v, __shfl_xor(v, 1));
  v = fmaxf(v, __shfl_xor(v, 2));
  v = fmaxf(v, __shfl_xor(v, 4));
  v = fmaxf(v, __shfl_xor(v, 8));
  return v;
}
__device__ __forceinline__ float redsum16(float v) {
  v += __shfl_xor(v, 1);
  v += __shfl_xor(v, 2);
  v += __shfl_xor(v, 4);
  v += __shfl_xor(v, 8);
  return v;
}

// ---------------------------------------------------------------- cvt f32->bf16
__global__ __launch_bounds__(256) void cvt_kernel(const float* __restrict__ in,
                                                  unsigned short* __restrict__ out,
                                                  int n4) {
  for (int i = blockIdx.x * 256 + threadIdx.x; i < n4; i += gridDim.x * 256) {
    const float4 v = reinterpret_cast<const float4*>(in)[i];
    ushort4 o;
    o.x = f2bf(v.x); o.y = f2bf(v.y); o.z = f2bf(v.z); o.w = f2bf(v.w);
    reinterpret_cast<ushort4*>(out)[i] = o;
  }
}

// ---------------------------------------------------------------- GEMM  C = A * Bt^T + bias
// A[M][K], Bt[N][K] row-major (both K-contiguous), C[M][N].
// 128x128 tile, BK=32, 256 threads (4 waves), each wave 64x64 = 4x4 16x16 frags.
template <int OUT_BF16>
__global__ __launch_bounds__(256) void gemm_bt(const unsigned short* __restrict__ A,
                                               const unsigned short* __restrict__ Bt,
                                               const float* __restrict__ bias,
                                               void* __restrict__ Cout,
                                               int M, int N, int K) {
  __shared__ __align__(16) unsigned short As[128 * 32];
  __shared__ __align__(16) unsigned short Bs[128 * 32];

  const int tid = threadIdx.x;
  const int w  = tid >> 6;         // wave 0..3
  const int l  = tid & 63;
  const int lr = l & 15;           // frag row lane
  const int lk = (l >> 4) * 8;     // frag k offset
  const int bm = blockIdx.y * 128;
  const int bn = blockIdx.x * 128;
  const int wr = (w >> 1) * 64;    // wave row offset in tile
  const int wc = (w & 1) * 64;     // wave col offset in tile

  f32x4 acc[4][4];
#pragma unroll
  for (int i = 0; i < 4; ++i)
#pragma unroll
    for (int j = 0; j < 4; ++j) acc[i][j] = (f32x4){0.f, 0.f, 0.f, 0.f};

  // staging: wave w stages rows [w*32, w*32+32) of each tile; 2 instr x 16 rows.
  // lane l covers LDS bytes base + 16*l  ->  row base + l/4, k-elem (l&3)*8
  const int srow = l >> 2;          // 0..15
  const int sk   = (l & 3) * 8;     // 0..24
  const unsigned short* Ab = A + (size_t)(bm + w * 32 + srow) * K + sk;
  const unsigned short* Bb = Bt + (size_t)(bn + w * 32 + srow) * K + sk;

  for (int kt = 0; kt < K; kt += 32) {
    gload_lds16(Ab + kt,                 &As[(w * 32 + 0) * 32]);
    gload_lds16(Ab + kt + (size_t)16 * K, &As[(w * 32 + 16) * 32]);
    gload_lds16(Bb + kt,                 &Bs[(w * 32 + 0) * 32]);
    gload_lds16(Bb + kt + (size_t)16 * K, &Bs[(w * 32 + 16) * 32]);
    __syncthreads();   // drains vmcnt before reads

    bf16x8 a[4], b[4];
#pragma unroll
    for (int mi = 0; mi < 4; ++mi)
      a[mi] = *reinterpret_cast<const bf16x8*>(&As[(wr + mi * 16 + lr) * 32 + lk]);
#pragma unroll
    for (int ni = 0; ni < 4; ++ni)
      b[ni] = *reinterpret_cast<const bf16x8*>(&Bs[(wc + ni * 16 + lr) * 32 + lk]);
#pragma unroll
    for (int mi = 0; mi < 4; ++mi)
#pragma unroll
      for (int ni = 0; ni < 4; ++ni)
        acc[mi][ni] = __builtin_amdgcn_mfma_f32_16x16x32_bf16(a[mi], b[ni], acc[mi][ni], 0, 0, 0);
    __syncthreads();   // before next stage overwrites LDS
  }

  // epilogue: D elem (reg i): row = 4*(l>>4)+i, col = l&15   [m89-verified]
  const int lg = l >> 4;
#pragma unroll
  for (int mi = 0; mi < 4; ++mi)
#pragma unroll
    for (int ni = 0; ni < 4; ++ni)
#pragma unroll
      for (int i = 0; i < 4; ++i) {
        const int row = bm + wr + mi * 16 + lg * 4 + i;
        const int col = bn + wc + ni * 16 + lr;
        const float v = acc[mi][ni][i] + bias[col];
        if (OUT_BF16)
          ((unsigned short*)Cout)[(size_t)row * N + col] = f2bf(v);
        else
          ((float*)Cout)[(size_t)row * N + col] = v;
      }
}

// ---------------------------------------------------------------- flash attention (causal)
// Block: 256 thr (4 waves), QBLK=128 (32 q-rows/wave), KVBLK=64, Dh=64.
// qkv row-major [8192][3072]: q at col 0, k at 1024, v at 2048; head h -> +h*64.
__global__ __launch_bounds__(256) void attn_fwd(const unsigned short* __restrict__ qkv,
                                                unsigned short* __restrict__ attn_out,
                                                const int* __restrict__ causal_flag) {
  __shared__ __align__(16) unsigned short Ks[64 * 64];
  __shared__ __align__(16) unsigned short Vt[64 * 64];     // V transposed: Vt[d][k]
  __shared__ __align__(16) unsigned short Ps[4][32 * 64];  // per-wave P tile

  const int tid = threadIdx.x;
  const int w  = tid >> 6;
  const int l  = tid & 63;
  const int lr = l & 15;
  const int lg = l >> 4;
  const int lk = lg * 8;
  const int qt = blockIdx.x;        // 0..15
  const int bh = blockIdx.y;        // 0..63
  const int b  = bh >> 4;
  const int h  = bh & 15;
  const int qbase = qt * 128;
  const int causal = causal_flag[0];

  const unsigned short* Qp = qkv + (size_t)(b * T_SEQ) * QKVN + h * DH;
  const unsigned short* Kp = Qp + D_EMB;
  const unsigned short* Vp = Qp + 2 * D_EMB;

  // Q fragments, reused across all KV tiles
  bf16x8 qf[2][2];
#pragma unroll
  for (int mi = 0; mi < 2; ++mi)
#pragma unroll
    for (int ks = 0; ks < 2; ++ks)
      qf[mi][ks] = *reinterpret_cast<const bf16x8*>(
          Qp + (size_t)(qbase + w * 32 + mi * 16 + lr) * QKVN + ks * 32 + lk);

  f32x4 oacc[2][4];
  float mrow[2][4], lsum[2][4];
#pragma unroll
  for (int mi = 0; mi < 2; ++mi) {
#pragma unroll
    for (int di = 0; di < 4; ++di) oacc[mi][di] = (f32x4){0.f, 0.f, 0.f, 0.f};
#pragma unroll
    for (int i = 0; i < 4; ++i) { mrow[mi][i] = -INFINITY; lsum[mi][i] = 0.f; }
  }

  const int nt = causal ? (qt * 2 + 2) : (T_SEQ / 64);

  for (int kb = 0; kb < nt; ++kb) {
    const int kbase = kb * 64;
    // stage K tile [64][64] via global_load_lds: wave w rows [w*16, w*16+16)
#pragma unroll
    for (int i = 0; i < 2; ++i) {
      const unsigned short* g =
          Kp + (size_t)(kbase + w * 16 + i * 8 + (l >> 3)) * QKVN + (l & 7) * 8;
      gload_lds16(g, &Ks[(w * 16 + i * 8) * 64]);
    }
    // stage V transposed (thread copy)
#pragma unroll
    for (int g2 = 0; g2 < 2; ++g2) {
      const int idx = tid + g2 * 256;
      const int k = idx & 63;
      const int d0 = (idx >> 6) * 8;
      bf16x8 v = *reinterpret_cast<const bf16x8*>(Vp + (size_t)(kbase + k) * QKVN + d0);
#pragma unroll
      for (int j = 0; j < 8; ++j)
        Vt[(d0 + j) * 64 + k] = ((unsigned short*)&v)[j];
    }
    __syncthreads();

    // S = Q K^T  (2x4 frags per wave)
    f32x4 s[2][4];
#pragma unroll
    for (int mi = 0; mi < 2; ++mi)
#pragma unroll
      for (int ni = 0; ni < 4; ++ni) s[mi][ni] = (f32x4){0.f, 0.f, 0.f, 0.f};
#pragma unroll
    for (int ks = 0; ks < 2; ++ks) {
      bf16x8 kf[4];
#pragma unroll
      for (int ni = 0; ni < 4; ++ni)
        kf[ni] = *reinterpret_cast<const bf16x8*>(&Ks[(ni * 16 + lr) * 64 + ks * 32 + lk]);
#pragma unroll
      for (int mi = 0; mi < 2; ++mi)
#pragma unroll
        for (int ni = 0; ni < 4; ++ni)
          s[mi][ni] = __builtin_amdgcn_mfma_f32_16x16x32_bf16(qf[mi][ks], kf[ni], s[mi][ni], 0, 0, 0);
    }

    // online softmax (row = qbase + w*32 + mi*16 + 4*lg + i ; col = kbase + ni*16 + lr)
#pragma unroll
    for (int mi = 0; mi < 2; ++mi) {
#pragma unroll
      for (int i = 0; i < 4; ++i) {
        const int qrow = qbase + w * 32 + mi * 16 + lg * 4 + i;
        float rmax = -INFINITY;
#pragma unroll
        for (int ni = 0; ni < 4; ++ni) {
          float v = s[mi][ni][i] * 0.125f;
          if (causal && (kbase + ni * 16 + lr > qrow)) v = -INFINITY;
          s[mi][ni][i] = v;
          rmax = fmaxf(rmax, v);
        }
        rmax = redmax16(rmax);
        const float mnew = fmaxf(mrow[mi][i], rmax);
        const float alpha = __expf(mrow[mi][i] - mnew);  // exp(-inf)=0 first iter
        mrow[mi][i] = mnew;
        float psum = 0.f;
#pragma unroll
        for (int ni = 0; ni < 4; ++ni) {
          const float p = __expf(s[mi][ni][i] - mnew);   // masked -> 0
          s[mi][ni][i] = p;
          psum += p;
        }
        psum = redsum16(psum);
        lsum[mi][i] = lsum[mi][i] * alpha + psum;
#pragma unroll
        for (int di = 0; di < 4; ++di) oacc[mi][di][i] *= alpha;
        // P -> LDS (bf16) for PV A-fragments
#pragma unroll
        for (int ni = 0; ni < 4; ++ni)
          Ps[w][(mi * 16 + lg * 4 + i) * 64 + ni * 16 + lr] = f2bf(s[mi][ni][i]);
      }
    }
    __syncthreads();

    // O += P V   (A = P from Ps[w], Bt = Vt)
#pragma unroll
    for (int ks2 = 0; ks2 < 2; ++ks2) {
      bf16x8 pf[2], vf[4];
#pragma unroll
      for (int mi = 0; mi < 2; ++mi)
        pf[mi] = *reinterpret_cast<const bf16x8*>(&Ps[w][(mi * 16 + lr) * 64 + ks2 * 32 + lk]);
#pragma unroll
      for (int di = 0; di < 4; ++di)
        vf[di] = *reinterpret_cast<const bf16x8*>(&Vt[(di * 16 + lr) * 64 + ks2 * 32 + lk]);
#pragma unroll
      for (int mi = 0; mi < 2; ++mi)
#pragma unroll
        for (int di = 0; di < 4; ++di)
          oacc[mi][di] = __builtin_amdgcn_mfma_f32_16x16x32_bf16(pf[mi], vf[di], oacc[mi][di], 0, 0, 0);
    }
    __syncthreads();
  }

  // epilogue: normalize and store bf16
#pragma unroll
  for (int mi = 0; mi < 2; ++mi)
#pragma unroll
    for (int di = 0; di < 4; ++di)
#pragma unroll
      for (int i = 0; i < 4; ++i) {
        const int q = qbase + w * 32 + mi * 16 + lg * 4 + i;
        const int d = di * 16 + lr;
        attn_out[(size_t)(b * T_SEQ + q) * D_EMB + h * DH + d] =
            f2bf(oacc[mi][di][i] / lsum[mi][i]);
      }
}

// ---------------------------------------------------------------- launch
extern "C" void kernel_launch(void* const* d_in, const int* in_sizes, int n_in,
                              void* d_out, int out_size, void* d_ws, size_t ws_size,
                              hipStream_t stream) {
  const float* x     = (const float*)d_in[0];
  const float* W_in  = (const float*)d_in[1];
  const float* b_in  = (const float*)d_in[2];
  const float* W_out = (const float*)d_in[3];
  const float* b_out = (const float*)d_in[4];
  const int*   causal = (const int*)d_in[5];
  float* out = (float*)d_out;

  char* ws = (char*)d_ws;
  unsigned short* x_bf    = (unsigned short*)(ws);
  unsigned short* win_bf  = (unsigned short*)(ws + 16777216);
  unsigned short* wout_bf = (unsigned short*)(ws + 23068672);
  unsigned short* qkv     = (unsigned short*)(ws + 25165824);
  unsigned short* attn    = (unsigned short*)(ws + 75497472);
  // total ws use: 92,274,688 bytes

  cvt_kernel<<<2048, 256, 0, stream>>>(x, x_bf, (MROWS * D_EMB) / 4);
  cvt_kernel<<<2048, 256, 0, stream>>>(W_in, win_bf, (QKVN * D_EMB) / 4);
  cvt_kernel<<<1024, 256, 0, stream>>>(W_out, wout_bf, (D_EMB * D_EMB) / 4);

  gemm_bt<1><<<dim3(QKVN / 128, MROWS / 128), 256, 0, stream>>>(
      x_bf, win_bf, b_in, qkv, MROWS, QKVN, D_EMB);

  attn_fwd<<<dim3(T_SEQ / 128, NB * NH), 256, 0, stream>>>(qkv, attn, causal);

  gemm_bt<0><<<dim3(D_EMB / 128, MROWS / 128), 256, 0, stream>>>(
      attn, wout_bf, b_out, out, MROWS, D_EMB, D_EMB);
}

// Round 2
// 342.995 us; speedup vs baseline: 1.4561x; 1.4561x over previous
//
#include <hip/hip_runtime.h>
#include <hip/hip_bf16.h>

// Problem constants (fixed by reference):
//   B=4, T=2048, C=1024, H=16, Dh=64, qkv N = 3072, M = B*T = 8192.
#define T_SEQ 2048
#define D_EMB 1024
#define NH    16
#define DH    64
#define NB    4
#define MROWS (NB * T_SEQ)      // 8192
#define QKVN  (3 * D_EMB)       // 3072

typedef __attribute__((ext_vector_type(8))) short bf16x8;   // 8 bf16 = 4 VGPR
typedef __attribute__((ext_vector_type(4))) float f32x4;

__device__ __forceinline__ unsigned short f2bf(float f) {
  __hip_bfloat16 h = __float2bfloat16(f);
  return __builtin_bit_cast(unsigned short, h);
}

__device__ __forceinline__ void gload_lds16(const void* g, void* lds) {
  __builtin_amdgcn_global_load_lds(
      (const __attribute__((address_space(1))) void*)g,
      (__attribute__((address_space(3))) void*)lds, 16, 0, 0);
}

__device__ __forceinline__ float redmax16(float v) {
  v = fmaxf(v, __shfl_xor(v, 1));
  v = fmaxf(v, __shfl_xor(v, 2));
  v = fmaxf(v, __shfl_xor(v, 4));
  v = fmaxf(v, __shfl_xor(v, 8));
  return v;
}
__device__ __forceinline__ float redsum16(float v) {
  v += __shfl_xor(v, 1);
  v += __shfl_xor(v, 2);
  v += __shfl_xor(v, 4);
  v += __shfl_xor(v, 8);
  return v;
}

// ---------------------------------------------------------------- cvt f32->bf16
__global__ __launch_bounds__(256) void cvt_kernel(const float* __restrict__ in,
                                                  unsigned short* __restrict__ out,
                                                  int n4) {
  for (int i = blockIdx.x * 256 + threadIdx.x; i < n4; i += gridDim.x * 256) {
    const float4 v = reinterpret_cast<const float4*>(in)[i];
    ushort4 o;
    o.x = f2bf(v.x); o.y = f2bf(v.y); o.z = f2bf(v.z); o.w = f2bf(v.w);
    reinterpret_cast<ushort4*>(out)[i] = o;
  }
}

// ---------------------------------------------------------------- GEMM  C = A * Bt^T + bias
// (unchanged this round — m97-style 128x128 tile, BK=32)
template <int OUT_BF16>
__global__ __launch_bounds__(256) void gemm_bt(const unsigned short* __restrict__ A,
                                               const unsigned short* __restrict__ Bt,
                                               const float* __restrict__ bias,
                                               void* __restrict__ Cout,
                                               int M, int N, int K) {
  __shared__ __align__(16) unsigned short As[128 * 32];
  __shared__ __align__(16) unsigned short Bs[128 * 32];

  const int tid = threadIdx.x;
  const int w  = tid >> 6;
  const int l  = tid & 63;
  const int lr = l & 15;
  const int lk = (l >> 4) * 8;
  const int bm = blockIdx.y * 128;
  const int bn = blockIdx.x * 128;
  const int wr = (w >> 1) * 64;
  const int wc = (w & 1) * 64;

  f32x4 acc[4][4];
#pragma unroll
  for (int i = 0; i < 4; ++i)
#pragma unroll
    for (int j = 0; j < 4; ++j) acc[i][j] = (f32x4){0.f, 0.f, 0.f, 0.f};

  const int srow = l >> 2;
  const int sk   = (l & 3) * 8;
  const unsigned short* Ab = A + (size_t)(bm + w * 32 + srow) * K + sk;
  const unsigned short* Bb = Bt + (size_t)(bn + w * 32 + srow) * K + sk;

  for (int kt = 0; kt < K; kt += 32) {
    gload_lds16(Ab + kt,                  &As[(w * 32 + 0) * 32]);
    gload_lds16(Ab + kt + (size_t)16 * K, &As[(w * 32 + 16) * 32]);
    gload_lds16(Bb + kt,                  &Bs[(w * 32 + 0) * 32]);
    gload_lds16(Bb + kt + (size_t)16 * K, &Bs[(w * 32 + 16) * 32]);
    __syncthreads();

    bf16x8 a[4], b[4];
#pragma unroll
    for (int mi = 0; mi < 4; ++mi)
      a[mi] = *reinterpret_cast<const bf16x8*>(&As[(wr + mi * 16 + lr) * 32 + lk]);
#pragma unroll
    for (int ni = 0; ni < 4; ++ni)
      b[ni] = *reinterpret_cast<const bf16x8*>(&Bs[(wc + ni * 16 + lr) * 32 + lk]);
#pragma unroll
    for (int mi = 0; mi < 4; ++mi)
#pragma unroll
      for (int ni = 0; ni < 4; ++ni)
        acc[mi][ni] = __builtin_amdgcn_mfma_f32_16x16x32_bf16(a[mi], b[ni], acc[mi][ni], 0, 0, 0);
    __syncthreads();
  }

  const int lg = l >> 4;
#pragma unroll
  for (int mi = 0; mi < 4; ++mi)
#pragma unroll
    for (int ni = 0; ni < 4; ++ni)
#pragma unroll
      for (int i = 0; i < 4; ++i) {
        const int row = bm + wr + mi * 16 + lg * 4 + i;
        const int col = bn + wc + ni * 16 + lr;
        const float v = acc[mi][ni][i] + bias[col];
        if (OUT_BF16)
          ((unsigned short*)Cout)[(size_t)row * N + col] = f2bf(v);
        else
          ((float*)Cout)[(size_t)row * N + col] = v;
      }
}

// ---------------------------------------------------------------- flash attention (causal)
// Block: 256 thr (4 waves). Each block processes TWO q-tiles (bx and 15-bx) of
// 128 rows each -> uniform causal work (36 KV-tiles/block). KVBLK=64, Dh=64.
// All LDS tiles XOR-swizzled: element (r,c) chunk j=c/8 stored at chunk j^(r&7)
// (byte ^= (r&7)<<4). K is staged via global_load_lds with PRE-SWIZZLED global
// source (linear LDS dest); V/P writes swizzle the store address directly.
__global__ __launch_bounds__(256) void attn_fwd(const unsigned short* __restrict__ qkv,
                                                unsigned short* __restrict__ attn_out,
                                                const int* __restrict__ causal_flag) {
  __shared__ __align__(16) unsigned short Ks[64 * 64];
  __shared__ __align__(16) unsigned short Vt[64 * 64];     // Vt[d][k] (swizzled)
  __shared__ __align__(16) unsigned short Ps[4][32 * 64];  // per-wave P (swizzled)

  const int tid = threadIdx.x;
  const int w  = tid >> 6;
  const int l  = tid & 63;
  const int lr = l & 15;
  const int lg = l >> 4;
  const int lk = lg * 8;
  const int bx = blockIdx.x;        // 0..7
  const int bh = blockIdx.y;        // 0..63
  const int b  = bh >> 4;
  const int h  = bh & 15;
  const int causal = causal_flag[0];

  const unsigned short* Qp = qkv + (size_t)(b * T_SEQ) * QKVN + h * DH;
  const unsigned short* Kp = Qp + D_EMB;
  const unsigned short* Vp = Qp + 2 * D_EMB;

  for (int qq = 0; qq < 2; ++qq) {
    const int qt = qq ? (15 - bx) : bx;
    const int qbase = qt * 128;

    // Q fragments (registers), reused across KV tiles
    bf16x8 qf[2][2];
#pragma unroll
    for (int mi = 0; mi < 2; ++mi)
#pragma unroll
      for (int ks = 0; ks < 2; ++ks)
        qf[mi][ks] = *reinterpret_cast<const bf16x8*>(
            Qp + (size_t)(qbase + w * 32 + mi * 16 + lr) * QKVN + ks * 32 + lk);

    f32x4 oacc[2][4];
    float mrow[2][4], lsum[2][4];
#pragma unroll
    for (int mi = 0; mi < 2; ++mi) {
#pragma unroll
      for (int di = 0; di < 4; ++di) oacc[mi][di] = (f32x4){0.f, 0.f, 0.f, 0.f};
#pragma unroll
      for (int i = 0; i < 4; ++i) { mrow[mi][i] = -INFINITY; lsum[mi][i] = 0.f; }
    }

    const int nt = causal ? (qt * 2 + 2) : (T_SEQ / 64);

    for (int kb = 0; kb < nt; ++kb) {
      const int kbase = kb * 64;
      // ---- stage K [64][64] swizzled: pre-swizzle the global source chunk.
      // lane l covers LDS row r = w*16 + i*8 + (l>>3), chunk j = l&7 (16B chunks).
      // LDS chunk j must hold original chunk j^(r&7)  (r&7 == l>>3 here).
#pragma unroll
      for (int i = 0; i < 2; ++i) {
        const int rloc = w * 16 + i * 8 + (l >> 3);
        const int cj   = (l & 7) ^ (l >> 3);
        gload_lds16(Kp + (size_t)(kbase + rloc) * QKVN + cj * 8,
                    &Ks[(w * 16 + i * 8) * 64]);
      }
      // ---- stage V transposed + swizzled (thread copy)
#pragma unroll
      for (int g2 = 0; g2 < 2; ++g2) {
        const int idx = tid + g2 * 256;
        const int k   = idx & 63;
        const int d0  = (idx >> 6) * 8;
        bf16x8 v = *reinterpret_cast<const bf16x8*>(Vp + (size_t)(kbase + k) * QKVN + d0);
#pragma unroll
        for (int j = 0; j < 8; ++j)   // row d0+j: (d0+j)&7 == j
          Vt[(d0 + j) * 64 + (k ^ (j << 3))] = ((unsigned short*)&v)[j];
      }
      __syncthreads();

      // ---- S = Q K^T
      f32x4 s[2][4];
#pragma unroll
      for (int mi = 0; mi < 2; ++mi)
#pragma unroll
        for (int ni = 0; ni < 4; ++ni) s[mi][ni] = (f32x4){0.f, 0.f, 0.f, 0.f};
#pragma unroll
      for (int ks = 0; ks < 2; ++ks) {
        bf16x8 kf[4];
#pragma unroll
        for (int ni = 0; ni < 4; ++ni) {
          const int R = ni * 16 + lr;
          kf[ni] = *reinterpret_cast<const bf16x8*>(
              &Ks[R * 64 + (((ks * 4 + lg) ^ (R & 7)) << 3)]);
        }
#pragma unroll
        for (int mi = 0; mi < 2; ++mi)
#pragma unroll
          for (int ni = 0; ni < 4; ++ni)
            s[mi][ni] = __builtin_amdgcn_mfma_f32_16x16x32_bf16(qf[mi][ks], kf[ni], s[mi][ni], 0, 0, 0);
      }

      // ---- online softmax. Mask only needed when tile touches the diagonal.
      const bool mm = causal && (kbase + 64 > qbase);
#pragma unroll
      for (int mi = 0; mi < 2; ++mi) {
#pragma unroll
        for (int i = 0; i < 4; ++i) {
          const int qrow = qbase + w * 32 + mi * 16 + lg * 4 + i;
          float rmax = -INFINITY;
#pragma unroll
          for (int ni = 0; ni < 4; ++ni) {
            float v = s[mi][ni][i] * 0.125f;
            if (mm && (kbase + ni * 16 + lr > qrow)) v = -INFINITY;
            s[mi][ni][i] = v;
            rmax = fmaxf(rmax, v);
          }
          rmax = redmax16(rmax);
          const float mnew = fmaxf(mrow[mi][i], rmax);
          const float alpha = __expf(mrow[mi][i] - mnew);
          mrow[mi][i] = mnew;
          float psum = 0.f;
#pragma unroll
          for (int ni = 0; ni < 4; ++ni) {
            const float p = __expf(s[mi][ni][i] - mnew);
            s[mi][ni][i] = p;
            psum += p;
          }
          psum = redsum16(psum);
          lsum[mi][i] = lsum[mi][i] * alpha + psum;
#pragma unroll
          for (int di = 0; di < 4; ++di) oacc[mi][di][i] *= alpha;
          const int rp = mi * 16 + lg * 4 + i;   // P row (swizzled store)
#pragma unroll
          for (int ni = 0; ni < 4; ++ni)
            Ps[w][rp * 64 + ((ni * 16 + lr) ^ ((rp & 7) << 3))] = f2bf(s[mi][ni][i]);
        }
      }
      __syncthreads();

      // ---- O += P V  (swizzled reads)
#pragma unroll
      for (int ks2 = 0; ks2 < 2; ++ks2) {
        bf16x8 pf[2], vf[4];
#pragma unroll
        for (int mi = 0; mi < 2; ++mi) {
          const int R = mi * 16 + lr;
          pf[mi] = *reinterpret_cast<const bf16x8*>(
              &Ps[w][R * 64 + (((ks2 * 4 + lg) ^ (R & 7)) << 3)]);
        }
#pragma unroll
        for (int di = 0; di < 4; ++di) {
          const int R = di * 16 + lr;
          vf[di] = *reinterpret_cast<const bf16x8*>(
              &Vt[R * 64 + (((ks2 * 4 + lg) ^ (R & 7)) << 3)]);
        }
#pragma unroll
        for (int mi = 0; mi < 2; ++mi)
#pragma unroll
          for (int di = 0; di < 4; ++di)
            oacc[mi][di] = __builtin_amdgcn_mfma_f32_16x16x32_bf16(pf[mi], vf[di], oacc[mi][di], 0, 0, 0);
      }
      __syncthreads();
    }

    // ---- epilogue: normalize + store bf16
#pragma unroll
    for (int mi = 0; mi < 2; ++mi) {
#pragma unroll
      for (int i = 0; i < 4; ++i) {
        const float inv = 1.0f / lsum[mi][i];
#pragma unroll
        for (int di = 0; di < 4; ++di) {
          const int q = qbase + w * 32 + mi * 16 + lg * 4 + i;
          const int d = di * 16 + lr;
          attn_out[(size_t)(b * T_SEQ + q) * D_EMB + h * DH + d] =
              f2bf(oacc[mi][di][i] * inv);
        }
      }
    }
  }
}

// ---------------------------------------------------------------- launch
extern "C" void kernel_launch(void* const* d_in, const int* in_sizes, int n_in,
                              void* d_out, int out_size, void* d_ws, size_t ws_size,
                              hipStream_t stream) {
  const float* x     = (const float*)d_in[0];
  const float* W_in  = (const float*)d_in[1];
  const float* b_in  = (const float*)d_in[2];
  const float* W_out = (const float*)d_in[3];
  const float* b_out = (const float*)d_in[4];
  const int*   causal = (const int*)d_in[5];
  float* out = (float*)d_out;

  char* ws = (char*)d_ws;
  unsigned short* x_bf    = (unsigned short*)(ws);
  unsigned short* win_bf  = (unsigned short*)(ws + 16777216);
  unsigned short* wout_bf = (unsigned short*)(ws + 23068672);
  unsigned short* qkv     = (unsigned short*)(ws + 25165824);
  unsigned short* attn    = (unsigned short*)(ws + 75497472);

  cvt_kernel<<<2048, 256, 0, stream>>>(x, x_bf, (MROWS * D_EMB) / 4);
  cvt_kernel<<<2048, 256, 0, stream>>>(W_in, win_bf, (QKVN * D_EMB) / 4);
  cvt_kernel<<<1024, 256, 0, stream>>>(W_out, wout_bf, (D_EMB * D_EMB) / 4);

  gemm_bt<1><<<dim3(QKVN / 128, MROWS / 128), 256, 0, stream>>>(
      x_bf, win_bf, b_in, qkv, MROWS, QKVN, D_EMB);

  attn_fwd<<<dim3(8, NB * NH), 256, 0, stream>>>(qkv, attn, causal);

  gemm_bt<0><<<dim3(D_EMB / 128, MROWS / 128), 256, 0, stream>>>(
      attn, wout_bf, b_out, out, MROWS, D_EMB, D_EMB);
}

// Round 7
// 322.534 us; speedup vs baseline: 1.5485x; 1.0634x over previous
//
#include <hip/hip_runtime.h>
#include <hip/hip_bf16.h>

// Problem constants (fixed by reference):
//   B=4, T=2048, C=1024, H=16, Dh=64, qkv N = 3072, M = B*T = 8192.
#define T_SEQ 2048
#define D_EMB 1024
#define NH    16
#define DH    64
#define NB    4
#define MROWS (NB * T_SEQ)      // 8192
#define QKVN  (3 * D_EMB)       // 3072

typedef __attribute__((ext_vector_type(8))) short bf16x8;   // 8 bf16 = 4 VGPR
typedef __attribute__((ext_vector_type(4))) float f32x4;

__device__ __forceinline__ unsigned short f2bf(float f) {
  __hip_bfloat16 h = __float2bfloat16(f);
  return __builtin_bit_cast(unsigned short, h);
}

__device__ __forceinline__ void gload_lds16(const void* g, void* lds) {
  __builtin_amdgcn_global_load_lds(
      (const __attribute__((address_space(1))) void*)g,
      (__attribute__((address_space(3))) void*)lds, 16, 0, 0);
}

__device__ __forceinline__ float redmax16(float v) {
  v = fmaxf(v, __shfl_xor(v, 1));
  v = fmaxf(v, __shfl_xor(v, 2));
  v = fmaxf(v, __shfl_xor(v, 4));
  v = fmaxf(v, __shfl_xor(v, 8));
  return v;
}
__device__ __forceinline__ float redsum16(float v) {
  v += __shfl_xor(v, 1);
  v += __shfl_xor(v, 2);
  v += __shfl_xor(v, 4);
  v += __shfl_xor(v, 8);
  return v;
}

// ---------------------------------------------------------------- cvt f32->bf16
__global__ __launch_bounds__(256) void cvt_kernel(const float* __restrict__ in,
                                                  unsigned short* __restrict__ out,
                                                  int n4) {
  for (int i = blockIdx.x * 256 + threadIdx.x; i < n4; i += gridDim.x * 256) {
    const float4 v = reinterpret_cast<const float4*>(in)[i];
    ushort4 o;
    o.x = f2bf(v.x); o.y = f2bf(v.y); o.z = f2bf(v.z); o.w = f2bf(v.w);
    reinterpret_cast<ushort4*>(out)[i] = o;
  }
}

// ---------------------------------------------------------------- GEMM  C = A * Bt^T + bias
// (unchanged — m97-style 128x128 tile, BK=32)
template <int OUT_BF16>
__global__ __launch_bounds__(256) void gemm_bt(const unsigned short* __restrict__ A,
                                               const unsigned short* __restrict__ Bt,
                                               const float* __restrict__ bias,
                                               void* __restrict__ Cout,
                                               int M, int N, int K) {
  __shared__ __align__(16) unsigned short As[128 * 32];
  __shared__ __align__(16) unsigned short Bs[128 * 32];

  const int tid = threadIdx.x;
  const int w  = tid >> 6;
  const int l  = tid & 63;
  const int lr = l & 15;
  const int lk = (l >> 4) * 8;
  const int bm = blockIdx.y * 128;
  const int bn = blockIdx.x * 128;
  const int wr = (w >> 1) * 64;
  const int wc = (w & 1) * 64;

  f32x4 acc[4][4];
#pragma unroll
  for (int i = 0; i < 4; ++i)
#pragma unroll
    for (int j = 0; j < 4; ++j) acc[i][j] = (f32x4){0.f, 0.f, 0.f, 0.f};

  const int srow = l >> 2;
  const int sk   = (l & 3) * 8;
  const unsigned short* Ab = A + (size_t)(bm + w * 32 + srow) * K + sk;
  const unsigned short* Bb = Bt + (size_t)(bn + w * 32 + srow) * K + sk;

  for (int kt = 0; kt < K; kt += 32) {
    gload_lds16(Ab + kt,                  &As[(w * 32 + 0) * 32]);
    gload_lds16(Ab + kt + (size_t)16 * K, &As[(w * 32 + 16) * 32]);
    gload_lds16(Bb + kt,                  &Bs[(w * 32 + 0) * 32]);
    gload_lds16(Bb + kt + (size_t)16 * K, &Bs[(w * 32 + 16) * 32]);
    __syncthreads();

    bf16x8 a[4], b[4];
#pragma unroll
    for (int mi = 0; mi < 4; ++mi)
      a[mi] = *reinterpret_cast<const bf16x8*>(&As[(wr + mi * 16 + lr) * 32 + lk]);
#pragma unroll
    for (int ni = 0; ni < 4; ++ni)
      b[ni] = *reinterpret_cast<const bf16x8*>(&Bs[(wc + ni * 16 + lr) * 32 + lk]);
#pragma unroll
    for (int mi = 0; mi < 4; ++mi)
#pragma unroll
      for (int ni = 0; ni < 4; ++ni)
        acc[mi][ni] = __builtin_amdgcn_mfma_f32_16x16x32_bf16(a[mi], b[ni], acc[mi][ni], 0, 0, 0);
    __syncthreads();
  }

  const int lg = l >> 4;
#pragma unroll
  for (int mi = 0; mi < 4; ++mi)
#pragma unroll
    for (int ni = 0; ni < 4; ++ni)
#pragma unroll
      for (int i = 0; i < 4; ++i) {
        const int row = bm + wr + mi * 16 + lg * 4 + i;
        const int col = bn + wc + ni * 16 + lr;
        const float v = acc[mi][ni][i] + bias[col];
        if (OUT_BF16)
          ((unsigned short*)Cout)[(size_t)row * N + col] = f2bf(v);
        else
          ((float*)Cout)[(size_t)row * N + col] = v;
      }
}

// ---------------------------------------------------------------- flash attention (causal)
// Block: 512 thr (8 waves). Each block processes TWO q-tiles (bx and 15-bx) of
// 128 rows; wave w owns rows [w*16, w*16+16). KVBLK=64, Dh=64.
// All LDS tiles XOR-swizzled (chunk j stored at j^(row&7)); K staged via
// global_load_lds with pre-swizzled global source.
__global__ __launch_bounds__(512, 4) void attn_fwd(const unsigned short* __restrict__ qkv,
                                                   unsigned short* __restrict__ attn_out,
                                                   const int* __restrict__ causal_flag) {
  __shared__ __align__(16) unsigned short Ks[64 * 64];
  __shared__ __align__(16) unsigned short Vt[64 * 64];     // Vt[d][k] (swizzled)
  __shared__ __align__(16) unsigned short Ps[8][16 * 64];  // per-wave P (swizzled)

  const int tid = threadIdx.x;
  const int w  = tid >> 6;          // wave 0..7
  const int l  = tid & 63;
  const int lr = l & 15;
  const int lg = l >> 4;
  const int lk = lg * 8;
  const int bx = blockIdx.x;        // 0..7
  const int bh = blockIdx.y;        // 0..63
  const int b  = bh >> 4;
  const int h  = bh & 15;
  const int causal = causal_flag[0];

  const unsigned short* Qp = qkv + (size_t)(b * T_SEQ) * QKVN + h * DH;
  const unsigned short* Kp = Qp + D_EMB;
  const unsigned short* Vp = Qp + 2 * D_EMB;

  for (int qq = 0; qq < 2; ++qq) {
    const int qt = qq ? (15 - bx) : bx;
    const int qbase = qt * 128;
    const int wrow0 = qbase + w * 16;          // this wave's first q-row

    // Q fragments, pre-scaled by 1/sqrt(Dh)=0.125 (exact: pow2 exponent shift)
    bf16x8 qf[2];
#pragma unroll
    for (int ks = 0; ks < 2; ++ks) {
      bf16x8 v = *reinterpret_cast<const bf16x8*>(
          Qp + (size_t)(wrow0 + lr) * QKVN + ks * 32 + lk);
#pragma unroll
      for (int j = 0; j < 8; ++j) {
        const float f = __builtin_bit_cast(float, ((unsigned)(unsigned short)v[j]) << 16) * 0.125f;
        v[j] = (short)(__builtin_bit_cast(unsigned, f) >> 16);
      }
      qf[ks] = v;
    }

    f32x4 oacc[4];
    float mrow[4], lsum[4];
#pragma unroll
    for (int di = 0; di < 4; ++di) oacc[di] = (f32x4){0.f, 0.f, 0.f, 0.f};
#pragma unroll
    for (int i = 0; i < 4; ++i) { mrow[i] = -INFINITY; lsum[i] = 0.f; }

    const int nt = causal ? (qt * 2 + 2) : (T_SEQ / 64);

    for (int kb = 0; kb < nt; ++kb) {
      const int kbase = kb * 64;
      // ---- stage K [64][64] swizzled: wave w rows [w*8, w*8+8)
      {
        const int cj = (l & 7) ^ (l >> 3);
        gload_lds16(Kp + (size_t)(kbase + w * 8 + (l >> 3)) * QKVN + cj * 8,
                    &Ks[(w * 8) * 64]);
      }
      // ---- stage V transposed + swizzled: 512 thr x 8 elems
      {
        const int k  = tid & 63;
        const int d0 = (tid >> 6) * 8;
        bf16x8 v = *reinterpret_cast<const bf16x8*>(Vp + (size_t)(kbase + k) * QKVN + d0);
#pragma unroll
        for (int j = 0; j < 8; ++j)
          Vt[(d0 + j) * 64 + (k ^ (j << 3))] = ((unsigned short*)&v)[j];
      }
      __syncthreads();

      // waves whose 16 rows are entirely above this KV tile skip compute
      const bool live = !causal || (kbase <= wrow0 + 15);
      if (live) {
        // ---- S = Q K^T  (1x4 frags)
        f32x4 s[4];
#pragma unroll
        for (int ni = 0; ni < 4; ++ni) s[ni] = (f32x4){0.f, 0.f, 0.f, 0.f};
#pragma unroll
        for (int ks = 0; ks < 2; ++ks) {
          bf16x8 kf[4];
#pragma unroll
          for (int ni = 0; ni < 4; ++ni) {
            const int R = ni * 16 + lr;
            kf[ni] = *reinterpret_cast<const bf16x8*>(
                &Ks[R * 64 + (((ks * 4 + lg) ^ (lr & 7)) << 3)]);
          }
#pragma unroll
          for (int ni = 0; ni < 4; ++ni)
            s[ni] = __builtin_amdgcn_mfma_f32_16x16x32_bf16(qf[ks], kf[ni], s[ni], 0, 0, 0);
        }

        // ---- online softmax; mask only if tile intersects this wave's rows
        const bool mm = causal && (kbase + 63 > wrow0);
#pragma unroll
        for (int i = 0; i < 4; ++i) {
          const int qrow = wrow0 + lg * 4 + i;
          float rmax = -INFINITY;
#pragma unroll
          for (int ni = 0; ni < 4; ++ni) {
            float v = s[ni][i];
            if (mm && (kbase + ni * 16 + lr > qrow)) v = -INFINITY;
            s[ni][i] = v;
            rmax = fmaxf(rmax, v);
          }
          rmax = redmax16(rmax);
          const float mnew = fmaxf(mrow[i], rmax);
          const float alpha = __expf(mrow[i] - mnew);
          mrow[i] = mnew;
          float psum = 0.f;
#pragma unroll
          for (int ni = 0; ni < 4; ++ni) {
            const float p = __expf(s[ni][i] - mnew);
            s[ni][i] = p;
            psum += p;
          }
          psum = redsum16(psum);
          lsum[i] = lsum[i] * alpha + psum;
#pragma unroll
          for (int di = 0; di < 4; ++di) oacc[di][i] *= alpha;
          const int rp = lg * 4 + i;
#pragma unroll
          for (int ni = 0; ni < 4; ++ni)
            Ps[w][rp * 64 + ((ni * 16 + lr) ^ ((rp & 7) << 3))] = f2bf(s[ni][i]);
        }

        // ---- O += P V (swizzled reads; Ps is per-wave, no barrier needed)
#pragma unroll
        for (int ks2 = 0; ks2 < 2; ++ks2) {
          bf16x8 pf, vf[4];
          pf = *reinterpret_cast<const bf16x8*>(
              &Ps[w][lr * 64 + (((ks2 * 4 + lg) ^ (lr & 7)) << 3)]);
#pragma unroll
          for (int di = 0; di < 4; ++di) {
            const int R = di * 16 + lr;
            vf[di] = *reinterpret_cast<const bf16x8*>(
                &Vt[R * 64 + (((ks2 * 4 + lg) ^ (lr & 7)) << 3)]);
          }
#pragma unroll
          for (int di = 0; di < 4; ++di)
            oacc[di] = __builtin_amdgcn_mfma_f32_16x16x32_bf16(pf, vf[di], oacc[di], 0, 0, 0);
        }
      }
      __syncthreads();
    }

    // ---- epilogue: normalize + store bf16
#pragma unroll
    for (int i = 0; i < 4; ++i) {
      const float inv = 1.0f / lsum[i];
#pragma unroll
      for (int di = 0; di < 4; ++di) {
        const int q = wrow0 + lg * 4 + i;
        const int d = di * 16 + lr;
        attn_out[(size_t)(b * T_SEQ + q) * D_EMB + h * DH + d] =
            f2bf(oacc[di][i] * inv);
      }
    }
  }
}

// ---------------------------------------------------------------- launch
extern "C" void kernel_launch(void* const* d_in, const int* in_sizes, int n_in,
                              void* d_out, int out_size, void* d_ws, size_t ws_size,
                              hipStream_t stream) {
  const float* x     = (const float*)d_in[0];
  const float* W_in  = (const float*)d_in[1];
  const float* b_in  = (const float*)d_in[2];
  const float* W_out = (const float*)d_in[3];
  const float* b_out = (const float*)d_in[4];
  const int*   causal = (const int*)d_in[5];
  float* out = (float*)d_out;

  char* ws = (char*)d_ws;
  unsigned short* x_bf    = (unsigned short*)(ws);
  unsigned short* win_bf  = (unsigned short*)(ws + 16777216);
  unsigned short* wout_bf = (unsigned short*)(ws + 23068672);
  unsigned short* qkv     = (unsigned short*)(ws + 25165824);
  unsigned short* attn    = (unsigned short*)(ws + 75497472);

  cvt_kernel<<<2048, 256, 0, stream>>>(x, x_bf, (MROWS * D_EMB) / 4);
  cvt_kernel<<<2048, 256, 0, stream>>>(W_in, win_bf, (QKVN * D_EMB) / 4);
  cvt_kernel<<<1024, 256, 0, stream>>>(W_out, wout_bf, (D_EMB * D_EMB) / 4);

  gemm_bt<1><<<dim3(QKVN / 128, MROWS / 128), 256, 0, stream>>>(
      x_bf, win_bf, b_in, qkv, MROWS, QKVN, D_EMB);

  attn_fwd<<<dim3(8, NB * NH), 512, 0, stream>>>(qkv, attn, causal);

  gemm_bt<0><<<dim3(D_EMB / 128, MROWS / 128), 256, 0, stream>>>(
      attn, wout_bf, b_out, out, MROWS, D_EMB, D_EMB);
}